// Round 1
// baseline (309.234 us; speedup 1.0000x reference)
//
#include <hip/hip_runtime.h>

// out[b,c,y,x] = sum_{dy,dx in [0,13)} aff[b, dy*13+dx, y, x] * in2_zp[b, c, y+dy-6, x+dx-6]
// B=4 C=64 H=W=192 D=169.
//
// Round 7: latency-bound restructure (all pipes were <30% at 187 us/dispatch):
//  * TY=2: block produces rows (y0, y0+1), streams the 14 shared in2 rows once
//    (halved staging + in2 refetch; 1 barrier per row vs 2 per dy per y).
//  * Double-buffered LDS staging, software-pipelined so every vmcnt wait is
//    covered by a ~700-cycle dot2 pass:
//      issue AfB+Sv -> pass B -> pack PB -> write Sv -> issue AfA -> pass A
//      -> pack PA -> barrier   (ONE barrier per row-iteration)
//  * 256-thread blocks (4 waves): 2 blocks/CU = exactly 2 waves on EVERY SIMD
//    (192-thr blocks left half the SIMDs with a single wave = zero coverage).
//  * XH=64, 4 channels/thread: acc = 32 VGPR, staging = 5 float4/thread;
//    peak liveness ~200 VGPR < 256 (launch_bounds(256,2) caps at 256).
//  * PITCHW=42 (42%32=10): the 16 cg's hit 16 distinct bank pairs -> <=2-way
//    conflicts (free) vs pitch-68's 4-way clusters.
//  * XCD swizzle: XCD g = bx&7 owns y-chunk [24g,24g+24) of one batch at a
//    time -> in2 rows are XCD-exclusive and L2-resident.
// Numerics identical to round 6 (same fp16 rtz packing, same tap order,
// fp32 accum) -> absmax ~0.05-0.5 as before.

#define KD   6
#define WIN  13
#define ND   169
#define NB   4
#define NC   64
#define NH   192
#define NW   192
#define XH   64            // x-tile width per block (3 tiles across W)
#define PITCHW 42          // LDS row pitch in 32-bit words (84 halves >= 80)
#define BUFW (NC * PITCHW) // 2688 words per buffer
#define NTH  256           // 4 waves

typedef _Float16 half2v __attribute__((ext_vector_type(2)));

static __device__ __forceinline__ half2v h2(unsigned u) {
    return __builtin_bit_cast(half2v, u);
}
static __device__ __forceinline__ unsigned pk(float a, float b) {
    return __builtin_bit_cast(unsigned, __builtin_amdgcn_cvt_pkrtz(a, b));
}

#if __has_builtin(__builtin_amdgcn_fdot2)
#define FDOT2(a, b, c) __builtin_amdgcn_fdot2((a), (b), (c), false)
#else
static __device__ __forceinline__ float fdot2_fb(half2v a, half2v b, float c) {
    return fmaf((float)a.x, (float)b.x, fmaf((float)a.y, (float)b.y, c));
}
#define FDOT2(a, b, c) fdot2_fb((a), (b), (c))
#endif

// Issue the 13 aff float4 loads for one (y, dy) row; ap already points at it.
static __device__ __forceinline__ void aff_issue(const float* __restrict__ ap,
                                                 float4 (&Af)[13]) {
#pragma unroll
    for (int dx = 0; dx < WIN; ++dx)
        Af[dx] = *(const float4*)&ap[(size_t)dx * (NH * NW)];
}

// Pack 13 float4 into dx-pair fp16 words: P[m][j] = (Af[2m]_j, Af[2m+1]_j),
// P[6][j] = (Af[12]_j, 0).
static __device__ __forceinline__ void aff_pack(const float4 (&Af)[13],
                                                unsigned (&P)[7][4]) {
#pragma unroll
    for (int m = 0; m < 6; ++m) {
        P[m][0] = pk(Af[2*m].x, Af[2*m+1].x);
        P[m][1] = pk(Af[2*m].y, Af[2*m+1].y);
        P[m][2] = pk(Af[2*m].z, Af[2*m+1].z);
        P[m][3] = pk(Af[2*m].w, Af[2*m+1].w);
    }
    P[6][0] = pk(Af[12].x, 0.f);
    P[6][1] = pk(Af[12].y, 0.f);
    P[6][2] = pk(Af[12].z, 0.f);
    P[6][3] = pk(Af[12].w, 0.f);
}

// One 13-tap pass for one y over this thread's 4 channels x 4 x's.
// wpb = buffer base + cg*PITCHW + 2*slot (thread's window word base, c = cg).
static __device__ __forceinline__ void pass_y(const unsigned* __restrict__ wpb,
                                              const unsigned (&P)[7][4],
                                              float (&acc)[4][4]) {
#pragma unroll
    for (int i = 0; i < 4; ++i) {                 // c = cg + 16*i
        const unsigned* wp = wpb + i * (16 * PITCHW);
        const uint2 t0 = *(const uint2*)&wp[0];
        const uint2 t1 = *(const uint2*)&wp[2];
        const uint2 t2 = *(const uint2*)&wp[4];
        const uint2 t3 = *(const uint2*)&wp[6];
        const uint2 t4 = *(const uint2*)&wp[8];
        const unsigned P1 = t0.y, P2 = t1.x, P3 = t1.y, P4 = t2.x;
        const unsigned P5 = t2.y, P6 = t3.x, P7 = t3.y, P8 = t4.x;
        const unsigned P9 = t4.y;
        const unsigned S1 = (P1 >> 16) | (P2 << 16);
        const unsigned S2 = (P2 >> 16) | (P3 << 16);
        const unsigned S3 = (P3 >> 16) | (P4 << 16);
        const unsigned S4 = (P4 >> 16) | (P5 << 16);
        const unsigned S5 = (P5 >> 16) | (P6 << 16);
        const unsigned S6 = (P6 >> 16) | (P7 << 16);
        const unsigned S7 = (P7 >> 16) | (P8 << 16);
        const unsigned S8 = (P8 >> 16) | (P9 << 16);

        float a0 = acc[i][0], a1 = acc[i][1], a2 = acc[i][2], a3 = acc[i][3];
        a0 = FDOT2(h2(P[0][0]), h2(P1), a0);
        a0 = FDOT2(h2(P[1][0]), h2(P2), a0);
        a0 = FDOT2(h2(P[2][0]), h2(P3), a0);
        a0 = FDOT2(h2(P[3][0]), h2(P4), a0);
        a0 = FDOT2(h2(P[4][0]), h2(P5), a0);
        a0 = FDOT2(h2(P[5][0]), h2(P6), a0);
        a0 = FDOT2(h2(P[6][0]), h2(P7), a0);
        a1 = FDOT2(h2(P[0][1]), h2(S1), a1);
        a1 = FDOT2(h2(P[1][1]), h2(S2), a1);
        a1 = FDOT2(h2(P[2][1]), h2(S3), a1);
        a1 = FDOT2(h2(P[3][1]), h2(S4), a1);
        a1 = FDOT2(h2(P[4][1]), h2(S5), a1);
        a1 = FDOT2(h2(P[5][1]), h2(S6), a1);
        a1 = FDOT2(h2(P[6][1]), h2(S7), a1);
        a2 = FDOT2(h2(P[0][2]), h2(P2), a2);
        a2 = FDOT2(h2(P[1][2]), h2(P3), a2);
        a2 = FDOT2(h2(P[2][2]), h2(P4), a2);
        a2 = FDOT2(h2(P[3][2]), h2(P5), a2);
        a2 = FDOT2(h2(P[4][2]), h2(P6), a2);
        a2 = FDOT2(h2(P[5][2]), h2(P7), a2);
        a2 = FDOT2(h2(P[6][2]), h2(P8), a2);
        a3 = FDOT2(h2(P[0][3]), h2(S2), a3);
        a3 = FDOT2(h2(P[1][3]), h2(S3), a3);
        a3 = FDOT2(h2(P[2][3]), h2(S4), a3);
        a3 = FDOT2(h2(P[3][3]), h2(S5), a3);
        a3 = FDOT2(h2(P[4][3]), h2(S6), a3);
        a3 = FDOT2(h2(P[5][3]), h2(S7), a3);
        a3 = FDOT2(h2(P[6][3]), h2(S8), a3);
        acc[i][0] = a0; acc[i][1] = a1; acc[i][2] = a2; acc[i][3] = a3;
    }
}

__global__ __launch_bounds__(NTH, 2)
void mxassemble(const float* __restrict__ aff,
                const float* __restrict__ in2,
                float* __restrict__ out) {
    __shared__ unsigned ldsw[2 * BUFW];   // 21504 B; word = 2 fp16 halves

    // XCD-partitioning swizzle: bx in [0,384) carries (xcd, b, by).
    const int bx = blockIdx.x;
    const int g  = bx & 7;                 // XCD (id % 8 round-robin)
    const int k  = bx >> 3;                // 0..47: within-XCD order
    const int b  = k / 12;                 // batch
    const int by = 12 * g + (k - 12 * b);  // y-block 0..95
    const int y0 = 2 * by;
    const int xb = blockIdx.y;             // x-tile 0..2
    const int X0 = xb * XH;

    const int t    = threadIdx.x;
    const int l    = t & 63;
    const int wv   = t >> 6;               // wave 0..3
    const int cg   = l & 15;               // channel group; c = cg + 16*i
    const int xs   = l >> 4;               // 0..3
    const int slot = wv * 4 + xs;          // 0..15
    const int x0   = X0 + slot * 4;

    // Row layout: half j in [0,80) <-> global x = X0 - 8 + j.
    // Zero the 8-half OOB aprons (xb=0: words 0..3; xb=2: words 36..39).
    if (xb != 1) {
        const int w0 = (xb == 0) ? 0 : 36;
        if (t < NC * 2) {
            const int c = t >> 1, qq = t & 1;
            *(uint2*)&ldsw[c * PITCHW + w0 + 2 * qq]        = make_uint2(0u, 0u);
            *(uint2*)&ldsw[BUFW + c * PITCHW + w0 + 2 * qq] = make_uint2(0u, 0u);
        }
    }

    // Staging slots (loop-invariant): item s covers (c, q) = 4 floats.
    // 64 channels x 20 chunks = 1280 items = 256 threads x 5 exactly.
    int wadr[5], goff[5];
#pragma unroll
    for (int s = 0; s < 5; ++s) {
        const int ii = t + NTH * s;
        const int c  = ii / 20;
        const int q  = ii - 20 * c;
        const int xg = X0 - 8 + 4 * q;
        const bool ok = (xg >= 0) && (xg < NW);
        wadr[s] = ok ? (c * PITCHW + 2 * q) : -1;
        goff[s] = c * (NH * NW) + xg;
    }

    float acc0[4][4], acc1[4][4];
#pragma unroll
    for (int i = 0; i < 4; ++i)
#pragma unroll
        for (int j = 0; j < 4; ++j) { acc0[i][j] = 0.f; acc1[i][j] = 0.f; }

    const float* in2_b  = in2 + (size_t)b * NC * NH * NW;
    const float* aff_y0 = aff + (size_t)b * ND * NH * NW + (size_t)y0 * NW + x0;
    const float* aff_y1 = aff_y0 + NW;
    const int wbase = cg * PITCHW + 2 * slot;

    float4 Af[13];
    unsigned PA[7][4], PB[7][4];

    // ---- prologue: PA = pack(aff(y0, dy=0)); stage row y0-6 into buf0 ----
    aff_issue(aff_y0, Af);
    if (y0 - KD >= 0) {
        const float* p = in2_b + (size_t)(y0 - KD) * NW;
        float4 Sv[5];
#pragma unroll
        for (int s = 0; s < 5; ++s)
            if (wadr[s] >= 0) Sv[s] = *(const float4*)&p[goff[s]];
#pragma unroll
        for (int s = 0; s < 5; ++s)
            if (wadr[s] >= 0) {
                uint2 w; w.x = pk(Sv[s].x, Sv[s].y); w.y = pk(Sv[s].z, Sv[s].w);
                *(uint2*)&ldsw[wadr[s]] = w;
            }
    }
    aff_pack(Af, PA);
    __syncthreads();

    const float* apB = aff_y1;                              // (y1, dy = rr)
    const float* apA = aff_y0 + (size_t)(WIN * NH * NW);    // (y0, dy = rr+1)

    for (int rr = 0; rr < 14; ++rr) {
        const int r = y0 - KD + rr;                 // row held in buf[rr&1]
        const bool rowvalid = (r >= 0) && (r < NH);
        const int rn = r + 1;
        const bool stage_next = (rr < 13) && (rn >= 0) && (rn < NH);
        unsigned* curw = ldsw + ((rr & 1) ? BUFW : 0);
        unsigned* nxtw = ldsw + ((rr & 1) ? 0 : BUFW);

        // 1. issue aff loads for next iteration's pass B: (y1, dy = rr)
        if (rr < 13) aff_issue(apB, Af);
        // 2. issue in2 staging loads for row rn
        float4 Sv[5];
        if (stage_next) {
            const float* p = in2_b + (size_t)rn * NW;
#pragma unroll
            for (int s = 0; s < 5; ++s)
                if (wadr[s] >= 0) Sv[s] = *(const float4*)&p[goff[s]];
        }
        // 3. pass B: y1, dy = rr-1 (PB packed last iter); covers 1 & 2
        if (rowvalid && rr >= 1) pass_y(curw + wbase, PB, acc1);
        // 4. pack PB for next iter (waits Af; Sv still outstanding -> vmcnt(5))
        if (rr < 13) aff_pack(Af, PB);
        // 5. staging write (Sv long since complete under pass B)
        if (stage_next) {
#pragma unroll
            for (int s = 0; s < 5; ++s)
                if (wadr[s] >= 0) {
                    uint2 w; w.x = pk(Sv[s].x, Sv[s].y); w.y = pk(Sv[s].z, Sv[s].w);
                    *(uint2*)&nxtw[wadr[s]] = w;
                }
        }
        // 6. issue aff loads for next iteration's pass A: (y0, dy = rr+1)
        if (rr < 12) aff_issue(apA, Af);
        // 7. pass A: y0, dy = rr (PA packed last iter); covers 6
        if (rowvalid && rr <= 12) pass_y(curw + wbase, PA, acc0);
        // 8. pack PA for next iter (wait covered by pass A)
        if (rr < 12) aff_pack(Af, PA);

        apB += (size_t)(WIN * NH * NW);
        apA += (size_t)(WIN * NH * NW);
        __syncthreads();   // single barrier per row-iteration (double buffer)
    }

    float* ob = out + (((size_t)b * NC + cg) * NH + y0) * NW + x0;
#pragma unroll
    for (int i = 0; i < 4; ++i) {
        *(float4*)&ob[(size_t)(16 * i) * NH * NW] =
            make_float4(acc0[i][0], acc0[i][1], acc0[i][2], acc0[i][3]);
        *(float4*)&ob[(size_t)(16 * i) * NH * NW + NW] =
            make_float4(acc1[i][0], acc1[i][1], acc1[i][2], acc1[i][3]);
    }
}

extern "C" void kernel_launch(void* const* d_in, const int* in_sizes, int n_in,
                              void* d_out, int out_size, void* d_ws, size_t ws_size,
                              hipStream_t stream) {
    const float* aff = (const float*)d_in[0];   // [4,169,192,192] f32
    const float* in2 = (const float*)d_in[1];   // [4, 64,192,192] f32
    float* outp = (float*)d_out;                // [4, 64,192,192] f32
    dim3 grid(384, 3, 1);                       // (xcd|b|y-block, x-tile)
    dim3 block(NTH);
    hipLaunchKernelGGL(mxassemble, grid, block, 0, stream, aff, in2, outp);
}